// Round 13
// baseline (237.982 us; speedup 1.0000x reference)
//
#include <hip/hip_runtime.h>
#include <hip/hip_bf16.h>
#include <math.h>

// Problem constants (from reference)
#define INPUT_DIM 1024
#define STATE_DIM 16
#define CONV_KK   4
#define INNER     2048          // INPUT_DIM * EXPAND
#define BATCH     2
#define SEQ       2048
#define M_TOT     (BATCH*SEQ)   // 4096
#define N1        (2*INNER)     // 4096
#define K1        INPUT_DIM     // 1024
#define N2        INPUT_DIM     // 1024
#define K2        INNER         // 2048
#define NCHUNK    64
#define CLEN      (SEQ/NCHUNK)  // 32

typedef __attribute__((ext_vector_type(8))) short short8;
typedef __attribute__((ext_vector_type(4))) float f32x4;
typedef unsigned short ushort;

#define LOG2E 1.44269504088896340736f

// ---- fast transcendentals (threshold is 1.16e-2; these are ~1e-6 rel) ----
__device__ __forceinline__ float fast_softplus(float x) {
    return x > 20.f ? x : __logf(1.f + __expf(x));
}
__device__ __forceinline__ float fast_silu(float x) {
    return x * __builtin_amdgcn_rcpf(1.f + __expf(-x));
}
__device__ __forceinline__ float exp2_fast(float t) {
#if __has_builtin(__builtin_amdgcn_exp2f)
    return __builtin_amdgcn_exp2f(t);      // v_exp_f32 (native exp2)
#else
    return __expf(t * 0.69314718055994531f);
#endif
}
__device__ __forceinline__ ushort f2bf(float f) {
    unsigned u = __float_as_uint(f);
    u = (u + 0x7FFF + ((u >> 16) & 1)) >> 16;   // RNE
    return (ushort)u;
}
__device__ __forceinline__ float bf2f(ushort u) {
    return __uint_as_float(((unsigned)u) << 16);
}

// ---------------------------------------------------------------------------
// Fused f32 -> bf16 convert for x, W_in, W_out (one kernel, 3 ranges).
// ---------------------------------------------------------------------------
__global__ __launch_bounds__(256) void cvt_bf16_fused(
        const float* __restrict__ x,   ushort* __restrict__ x_bf,
        const float* __restrict__ wi,  ushort* __restrict__ wi_bf,
        const float* __restrict__ wo,  ushort* __restrict__ wo_bf)
{
    const int NA = M_TOT * K1 / 8;        // 524288
    const int NB = N1 * K1 / 8;           // 524288
    int i = blockIdx.x * 256 + threadIdx.x;
    const float* in; ushort* out; int idx;
    if (i < NA)            { in = x;  out = x_bf;  idx = i; }
    else if (i < NA + NB)  { in = wi; out = wi_bf; idx = i - NA; }
    else                   { in = wo; out = wo_bf; idx = i - NA - NB; }
    const float4* p = (const float4*)in + (size_t)idx * 2;
    float4 v0 = p[0], v1 = p[1];
    ushort u[8] = { f2bf(v0.x), f2bf(v0.y), f2bf(v0.z), f2bf(v0.w),
                    f2bf(v1.x), f2bf(v1.y), f2bf(v1.z), f2bf(v1.w) };
    *(short8*)(out + (size_t)idx * 8) = *(short8*)u;
}

// ---------------------------------------------------------------------------
// bf16 MFMA GEMM, NT form: C[m][n] = sum_k A[m*K+k]*B[n*K+k].
// BK=64 + conflict-free both-sides XOR swizzle (verified r7: conflicts = 0).
// OBF: output bf16 (GEMM1 -> xr) or f32 (GEMM2 -> out).
// ---------------------------------------------------------------------------
template<int BM, int BN, int WROWS, int WCOLS, bool OBF>
__global__ __launch_bounds__(256) void gemm_bf16_nt(
        const ushort* __restrict__ A, const ushort* __restrict__ B,
        void* __restrict__ Cout, int M, int N, int K)
{
    constexpr int MR = BM / WROWS / 16;
    constexpr int NR = BN / WCOLS / 16;
    __shared__ ushort As[BM][64];
    __shared__ ushort Bs[BN][64];

    const int tid  = threadIdx.x;
    const int w    = tid >> 6;
    const int lane = tid & 63;
    const int bm   = blockIdx.y * BM;
    const int bn   = blockIdx.x * BN;
    const int wm0  = (w / WCOLS) * (BM / WROWS);
    const int wn0  = (w % WCOLS) * (BN / WCOLS);

    const int srow  = lane >> 3;                       // row within 8-row chunk
    const int sslot = (lane & 7) ^ srow;               // pre-swizzled src slot
    const int scol  = sslot * 8;

    f32x4 acc[MR][NR] = {};

    for (int k0 = 0; k0 < K; k0 += 64) {
        __syncthreads();
#pragma unroll
        for (int j8 = w; j8 < BM / 8; j8 += 4) {
            const ushort* ga = A + (size_t)(bm + j8 * 8 + srow) * K + k0 + scol;
            __builtin_amdgcn_global_load_lds(
                (const __attribute__((address_space(1))) void*)ga,
                (__attribute__((address_space(3))) void*)&As[j8 * 8][0], 16, 0, 0);
        }
#pragma unroll
        for (int j8 = w; j8 < BN / 8; j8 += 4) {
            const ushort* gb = B + (size_t)(bn + j8 * 8 + srow) * K + k0 + scol;
            __builtin_amdgcn_global_load_lds(
                (const __attribute__((address_space(1))) void*)gb,
                (__attribute__((address_space(3))) void*)&Bs[j8 * 8][0], 16, 0, 0);
        }
        __syncthreads();

#pragma unroll
        for (int ks = 0; ks < 2; ks++) {
            const int lslot = ks * 4 + (lane >> 4);
            const int pcol  = (lslot ^ (lane & 7)) * 8;
            short8 a[MR], b[NR];
#pragma unroll
            for (int i = 0; i < MR; i++)
                a[i] = *(const short8*)&As[wm0 + i * 16 + (lane & 15)][pcol];
#pragma unroll
            for (int j = 0; j < NR; j++)
                b[j] = *(const short8*)&Bs[wn0 + j * 16 + (lane & 15)][pcol];
#pragma unroll
            for (int i = 0; i < MR; i++)
#pragma unroll
                for (int j = 0; j < NR; j++)
                    acc[i][j] = __builtin_amdgcn_mfma_f32_16x16x32_bf16(
                        a[i], b[j], acc[i][j], 0, 0, 0);
        }
    }

    // epilogue: D row=(lane>>4)*4+r, col=lane&15  [verified m89/m91]
#pragma unroll
    for (int i = 0; i < MR; i++)
#pragma unroll
        for (int j = 0; j < NR; j++)
#pragma unroll
            for (int r = 0; r < 4; r++) {
                int row = bm + wm0 + i * 16 + (lane >> 4) * 4 + r;
                int col = bn + wn0 + j * 16 + (lane & 15);
                if constexpr (OBF)
                    ((ushort*)Cout)[(size_t)row * N + col] = f2bf(acc[i][j][r]);
                else
                    ((float*)Cout)[(size_t)row * N + col] = acc[i][j][r];
            }
}

// ---------------------------------------------------------------------------
// Scan pass A (fused conv+SiLU): one thread per (b,chunk,c), 16 states in
// registers; 4-step load batching; exp2 with pre-scaled negA2. xr is bf16.
// Hc layout: [B][NCHUNK][16][INNER] ; Dsum: [B][NCHUNK][INNER]
// ---------------------------------------------------------------------------
__global__ __launch_bounds__(256) void scan_stats_fused(
        const ushort* __restrict__ xr,      // (B*S, 4096) bf16
        const float* __restrict__ conv_w,   // (INNER,1,4)
        const float* __restrict__ conv_b,   // (INNER)
        const float* __restrict__ A_log,    // (INNER,16)
        float* __restrict__ Hc,
        float* __restrict__ Dsum)
{
    const int gid = blockIdx.x * 256 + threadIdx.x;   // (b, chunk, c), c fastest
    const int c     = gid & (INNER - 1);
    const int chunk = (gid >> 11) & (NCHUNK - 1);
    const int b     = gid >> 17;

    const float4 w4  = *(const float4*)(conv_w + c * 4);
    const float bias = conv_b[c];

    float negA2[16];   // -exp(A_log) * log2(e)
    {
        const float4* ap = (const float4*)(A_log + c * 16);
#pragma unroll
        for (int q = 0; q < 4; q++) {
            float4 v = ap[q];
            negA2[q*4+0] = -__expf(v.x) * LOG2E; negA2[q*4+1] = -__expf(v.y) * LOG2E;
            negA2[q*4+2] = -__expf(v.z) * LOG2E; negA2[q*4+3] = -__expf(v.w) * LOG2E;
        }
    }

    const int s0 = chunk * CLEN;
    const ushort* xp = xr + ((size_t)(b * SEQ + s0)) * N1 + c;

    float xm1 = 0.f, xm2 = 0.f, xm3 = 0.f;
    if (s0 > 0) { xm1 = bf2f(xp[-N1]); xm2 = bf2f(xp[-2*N1]); xm3 = bf2f(xp[-3*N1]); }

    float h[16] = {};
    float dsum = 0.f;
    for (int s4 = 0; s4 < CLEN; s4 += 4) {
        float xv[4];
#pragma unroll
        for (int j = 0; j < 4; j++)
            xv[j] = bf2f(xp[(size_t)(s4 + j) * N1]);
#pragma unroll
        for (int j = 0; j < 4; j++) {
            float x0  = xv[j];
            float a4  = bias + w4.x*xm3 + w4.y*xm2 + w4.z*xm1 + w4.w*x0;
            xm3 = xm2; xm2 = xm1; xm1 = x0;
            float xc    = fast_silu(a4);
            float delta = fast_softplus(xc);
            dsum += delta;
            float bx = xc * xc;
#pragma unroll
            for (int st = 0; st < 16; st++)
                h[st] = exp2_fast(delta * negA2[st]) * h[st] + bx;
        }
    }

    const size_t cb = (size_t)b * NCHUNK + chunk;
#pragma unroll
    for (int st = 0; st < 16; st++)
        Hc[(cb * 16 + st) * INNER + c] = h[st];
    Dsum[cb * INNER + c] = dsum;
}

// ---------------------------------------------------------------------------
// Pass B: carry propagation across NCHUNK chunks; Hc becomes init states.
// ---------------------------------------------------------------------------
__global__ __launch_bounds__(256) void scan_carry(
        float* __restrict__ Hc,
        const float* __restrict__ Dsum,
        const float* __restrict__ A_log)
{
    const int tid = blockIdx.x * 256 + threadIdx.x;
    const int c  = tid & (INNER - 1);
    const int st = (tid >> 11) & 15;
    const int b  = tid >> 15;

    const float negA2 = -__expf(A_log[c * STATE_DIM + st]) * LOG2E;
    float carry = 0.f;
#pragma unroll 4
    for (int j = 0; j < NCHUNK; j++) {
        const size_t cb  = (size_t)b * NCHUNK + j;
        const size_t idx = (cb * 16 + st) * INNER + c;
        float hend = Hc[idx];
        float P    = exp2_fast(Dsum[cb * INNER + c] * negA2);
        Hc[idx] = carry;
        carry = P * carry + hend;
    }
}

// ---------------------------------------------------------------------------
// Pass C (fused conv+SiLU + scan + gating): recompute chunk from init state,
// emit y as bf16. 4-step load batching. xr is bf16.
// ---------------------------------------------------------------------------
__global__ __launch_bounds__(256) void scan_apply_fused(
        const ushort* __restrict__ xr,      // bf16
        const float* __restrict__ conv_w,
        const float* __restrict__ conv_b,
        const float* __restrict__ A_log,
        const float* __restrict__ Dv,
        const float* __restrict__ Hc,       // init states
        ushort* __restrict__ y_bf)          // (B*S, INNER) bf16
{
    const int gid = blockIdx.x * 256 + threadIdx.x;
    const int c     = gid & (INNER - 1);
    const int chunk = (gid >> 11) & (NCHUNK - 1);
    const int b     = gid >> 17;

    const float4 w4  = *(const float4*)(conv_w + c * 4);
    const float bias = conv_b[c];
    const float Dc   = Dv[c];

    float negA2[16];
    {
        const float4* ap = (const float4*)(A_log + c * 16);
#pragma unroll
        for (int q = 0; q < 4; q++) {
            float4 v = ap[q];
            negA2[q*4+0] = -__expf(v.x) * LOG2E; negA2[q*4+1] = -__expf(v.y) * LOG2E;
            negA2[q*4+2] = -__expf(v.z) * LOG2E; negA2[q*4+3] = -__expf(v.w) * LOG2E;
        }
    }

    const int s0 = chunk * CLEN;
    const size_t row0 = (size_t)(b * SEQ + s0);
    const ushort* xp = xr + row0 * N1 + c;
    const ushort* rp = xr + row0 * N1 + INNER + c;
    ushort*      yp = y_bf + row0 * INNER + c;

    float xm1 = 0.f, xm2 = 0.f, xm3 = 0.f;
    if (s0 > 0) { xm1 = bf2f(xp[-N1]); xm2 = bf2f(xp[-2*N1]); xm3 = bf2f(xp[-3*N1]); }

    const size_t cb = (size_t)b * NCHUNK + chunk;
    float h[16];
#pragma unroll
    for (int st = 0; st < 16; st++)
        h[st] = Hc[(cb * 16 + st) * INNER + c];

    for (int s4 = 0; s4 < CLEN; s4 += 4) {
        float xv[4], rv[4];
#pragma unroll
        for (int j = 0; j < 4; j++) {
            xv[j] = bf2f(xp[(size_t)(s4 + j) * N1]);
            rv[j] = bf2f(rp[(size_t)(s4 + j) * N1]);
        }
#pragma unroll
        for (int j = 0; j < 4; j++) {
            float x0  = xv[j];
            float a4  = bias + w4.x*xm3 + w4.y*xm2 + w4.z*xm1 + w4.w*x0;
            xm3 = xm2; xm2 = xm1; xm1 = x0;
            float xc    = fast_silu(a4);
            float delta = fast_softplus(xc);
            float bx    = xc * xc;
#pragma unroll
            for (int st = 0; st < 16; st++)
                h[st] = exp2_fast(delta * negA2[st]) * h[st] + bx;

            float s01 = (h[0]+h[1]) + (h[2]+h[3]);
            float s23 = (h[4]+h[5]) + (h[6]+h[7]);
            float s45 = (h[8]+h[9]) + (h[10]+h[11]);
            float s67 = (h[12]+h[13]) + (h[14]+h[15]);
            float sum = (s01 + s23) + (s45 + s67);

            float r = rv[j];
            float y = xc * sum * fast_silu(r) + Dc * xc;
            yp[(size_t)(s4 + j) * INNER] = f2bf(y);
        }
    }
}

// ---------------------------------------------------------------------------
extern "C" void kernel_launch(void* const* d_in, const int* in_sizes, int n_in,
                              void* d_out, int out_size, void* d_ws, size_t ws_size,
                              hipStream_t stream)
{
    const float* x      = (const float*)d_in[0];
    const float* W_in   = (const float*)d_in[1];
    const float* conv_w = (const float*)d_in[2];
    const float* conv_b = (const float*)d_in[3];
    const float* A_log  = (const float*)d_in[4];
    const float* Dv     = (const float*)d_in[5];
    const float* W_out  = (const float*)d_in[6];
    float* out = (float*)d_out;

    // workspace layout (bytes): 32 (xr bf16) + 16 + 0.5 + 8 + 8 + 4 + 16 MB
    char* ws = (char*)d_ws;
    ushort* xr      = (ushort*)ws;  ws += (size_t)M_TOT * N1 * 2;
    float*  Hc      = (float*)ws;   ws += (size_t)BATCH * NCHUNK * STATE_DIM * INNER * 4;
    float*  Dsum    = (float*)ws;   ws += (size_t)BATCH * NCHUNK * INNER * 4;
    ushort* x_bf    = (ushort*)ws;  ws += (size_t)M_TOT * K1 * 2;
    ushort* Win_bf  = (ushort*)ws;  ws += (size_t)N1 * K1 * 2;
    ushort* Wout_bf = (ushort*)ws;  ws += (size_t)N2 * K2 * 2;
    ushort* y_bf    = (ushort*)ws;  ws += (size_t)M_TOT * INNER * 2;

    // 0) fused f32 -> bf16 converts (x, W_in, W_out)
    {
        const int total8 = (M_TOT * K1 + N1 * K1 + N2 * K2) / 8;   // 1310720
        cvt_bf16_fused<<<total8 / 256, 256, 0, stream>>>(
            x, x_bf, W_in, Win_bf, W_out, Wout_bf);
    }

    // 1) xr = x @ W_in.T  (4096 x 4096, K=1024) -- bf16 MFMA, bf16 output
    gemm_bf16_nt<128,128,2,2,true><<<dim3(N1/128, M_TOT/128), 256, 0, stream>>>(
        x_bf, Win_bf, xr, M_TOT, N1, K1);

    // 2) chunked selective scan with fused depthwise conv + SiLU + gating
    scan_stats_fused<<<(BATCH * NCHUNK * INNER) / 256, 256, 0, stream>>>(
        xr, conv_w, conv_b, A_log, Hc, Dsum);
    scan_carry<<<(BATCH * STATE_DIM * INNER) / 256, 256, 0, stream>>>(
        Hc, Dsum, A_log);
    scan_apply_fused<<<(BATCH * NCHUNK * INNER) / 256, 256, 0, stream>>>(
        xr, conv_w, conv_b, A_log, Dv, Hc, y_bf);

    // 3) out = y @ W_out.T  (4096 x 1024, K=2048) -- bf16 MFMA, f32 output
    gemm_bf16_nt<128,64,2,2,false><<<dim3(N2/64, M_TOT/128), 256, 0, stream>>>(
        y_bf, Wout_bf, out, M_TOT, N2, K2);
}